// Round 4
// baseline (1608.830 us; speedup 1.0000x reference)
//
#include <hip/hip_runtime.h>
#include <hip/hip_bf16.h>

#define B_   4
#define LD_  1024
#define LE_  1024
#define D_   256
#define H_   8
#define DK_  32
#define DFF_ 1024
#define NL_  6
#define NTOK (B_ * LD_)   // 4096 decoder tokens; encoder also 4*1024 = 4096
#define M1E  1048576      // NTOK * D_ elements

typedef __hip_bfloat16 bf16;
typedef __bf16 bf16_t;
typedef bf16_t bf16x8 __attribute__((ext_vector_type(8)));
typedef bf16_t bf16x4 __attribute__((ext_vector_type(4)));
typedef float  f32x4  __attribute__((ext_vector_type(4)));

__device__ __forceinline__ float bits2f(unsigned short u) {
    union { unsigned int i; float f; } w; w.i = ((unsigned int)u) << 16; return w.f;
}
// dtype-flexible scalar load from tensor base + element index
__device__ __forceinline__ float ldx(const void* p, size_t i, int f32) {
    if (f32) return ((const float*)p)[i];
    return bits2f(((const unsigned short*)p)[i]);
}

// ---------------------------------------------------------------------------
// Detect input dtype (bf16 vs fp32). flag: 1=fp32, 0=bf16.
__global__ __launch_bounds__(256) void detect_kernel(
    const void* __restrict__ enc, int* __restrict__ flag)
{
    __shared__ int bad;
    if (threadIdx.x == 0) bad = 0;
    __syncthreads();
    const unsigned short* u = (const unsigned short*)enc;
    int b = 0;
    for (int i = threadIdx.x; i < 4096; i += 256) {
        unsigned short e = (u[i] >> 7) & 0xFF;
        if (e >= 142) b = 1;
    }
    if (b) atomicOr(&bad, 1);
    __syncthreads();
    if (threadIdx.x == 0) *flag = bad;
}

// ---------------------------------------------------------------------------
// build PE table [1024][256] once
__global__ __launch_bounds__(256) void pe_build_kernel(float* __restrict__ pe)
{
    int i = blockIdx.x * 256 + threadIdx.x;     // over LD_*D_ = 262144
    int d = i & (D_ - 1);
    int pos = i >> 8;
    int j = d & 127;
    float inv = powf(10000.0f, -2.0f * (float)j / (float)D_);
    float s = (float)pos * inv;
    pe[i] = (d < 128) ? sinf(s) : cosf(s);
}

// x = embed + PE (layer-0 PE fused here)
__global__ __launch_bounds__(256) void embed_kernel(
    const void* __restrict__ dec, const void* __restrict__ Wt,
    const void* __restrict__ bt, float* __restrict__ x,
    const float* __restrict__ pe, const int* __restrict__ flag)
{
    int f32 = *flag;
    int i = blockIdx.x * 256 + threadIdx.x;     // over NTOK * D_
    int d = i & (D_ - 1);
    int t = i >> 8;
    float a0 = ldx(dec, t * 3 + 0, f32);
    float a1 = ldx(dec, t * 3 + 1, f32);
    float a2 = ldx(dec, t * 3 + 2, f32);
    x[i] = ldx(bt, d, f32) + a0 * ldx(Wt, 0 * D_ + d, f32)
         + a1 * ldx(Wt, 1 * D_ + d, f32) + a2 * ldx(Wt, 2 * D_ + d, f32)
         + pe[i & (LD_ * D_ - 1)];
}

__global__ __launch_bounds__(256) void conv_kernel(
    const void* __restrict__ in, float* __restrict__ out, const int* __restrict__ flag)
{
    int f32 = *flag;
    int i = blockIdx.x * 256 + threadIdx.x;
    out[i] = ldx(in, i, f32);
}

// ---------------------------------------------------------------------------
// MFMA GEMM: C = A @ W + bias (optional relu). A fp32 [M,K]; W,bias dtype per
// flag; wOff/bOff = element offsets of the layer slice. z-batched over up to 3
// independent (A,W,bias,C) tuples.
//
// mode 0: C fp32 [M][N] (+optional relu)
// mode 1: attention-prep epilogue (N==256):
//   z==0: Q -> (q+b)*scale split to hi/lo bf16: C[idx], C[M1E+idx]
//   z==1: K -> split hi/lo bf16 likewise
//   z==2: V -> bf16, TRANSPOSED: C[(size_t)n * 4096 + m]  (Vt layout [256][4096])
__global__ __launch_bounds__(256) void gemm3_kernel(
    const float* __restrict__ A0, const float* __restrict__ A1, const float* __restrict__ A2,
    const void* __restrict__ W0, const void* __restrict__ W1, const void* __restrict__ W2,
    const void* __restrict__ bias0, const void* __restrict__ bias1, const void* __restrict__ bias2,
    float* __restrict__ C0, float* __restrict__ C1, float* __restrict__ C2,
    size_t wOff, size_t bOff,
    int M, int N, int K, int relu, int mode, const int* __restrict__ flag)
{
    const int f32 = *flag;
    const int z = blockIdx.z;
    const float* A = (z == 0) ? A0 : (z == 1) ? A1 : A2;
    const void*  W = (z == 0) ? W0 : (z == 1) ? W1 : W2;
    const void*  bias = (z == 0) ? bias0 : (z == 1) ? bias1 : bias2;
    float* C = (z == 0) ? C0 : (z == 1) ? C1 : C2;

    __shared__ __align__(16) bf16_t Ahi[32][40];
    __shared__ __align__(16) bf16_t Alo[32][40];
    __shared__ __align__(16) bf16_t Whi[64][40];
    __shared__ __align__(16) bf16_t Wlo[64][40];

    const int tid = threadIdx.x;
    const int m0 = blockIdx.y * 32, n0 = blockIdx.x * 64;
    const int w = tid >> 6, l = tid & 63, l15 = l & 15, lg = l >> 4;
    const int wr = w >> 1, wc = w & 1;

    // A staging: thread -> (row 0..31, 4-float group)
    const int ar = tid >> 3, ac = (tid & 7) * 4;
    // W staging: thread -> (col n 0..63, k-block 0..3); swizzled block index
    const int wn = tid & 63, wkg = tid >> 6;
    const int wkb = 8 * (wkg ^ ((wn >> 3) & 3));

    // fragment read indices (hoisted)
    const int fa = 16 * wr + l15;
    const int c0 = 32 * wc + l15, c1 = c0 + 16;
    const int kb0 = 8 * (lg ^ ((c0 >> 3) & 3));
    const int kb1 = 8 * (lg ^ ((c1 >> 3) & 3));

    f32x4 acc0 = {0.f, 0.f, 0.f, 0.f};
    f32x4 acc1 = {0.f, 0.f, 0.f, 0.f};

    // prefetch K-step 0
    float4 av = *(const float4*)&A[(size_t)(m0 + ar) * K + ac];
    float wf[8];
#pragma unroll
    for (int j = 0; j < 8; ++j)
        wf[j] = ldx(W, wOff + (size_t)(8 * wkg + j) * N + n0 + wn, f32);

    for (int k0 = 0; k0 < K; k0 += 32) {
        __syncthreads();
        {   // convert staged regs -> hi/lo LDS
            float af[4] = {av.x, av.y, av.z, av.w};
            bf16x4 h4, l4;
#pragma unroll
            for (int j = 0; j < 4; ++j) {
                bf16_t hv = (bf16_t)af[j];
                h4[j] = hv;
                l4[j] = (bf16_t)(af[j] - (float)hv);
            }
            *(bf16x4*)&Ahi[ar][ac] = h4;
            *(bf16x4*)&Alo[ar][ac] = l4;
            bf16x8 h8, l8;
#pragma unroll
            for (int j = 0; j < 8; ++j) {
                bf16_t hv = (bf16_t)wf[j];
                h8[j] = hv;
                l8[j] = (bf16_t)(wf[j] - (float)hv);
            }
            *(bf16x8*)&Whi[wn][wkb] = h8;
            *(bf16x8*)&Wlo[wn][wkb] = l8;
        }
        __syncthreads();

        // prefetch next K-step while MFMAs run
        if (k0 + 32 < K) {
            av = *(const float4*)&A[(size_t)(m0 + ar) * K + k0 + 32 + ac];
#pragma unroll
            for (int j = 0; j < 8; ++j)
                wf[j] = ldx(W, wOff + (size_t)(k0 + 32 + 8 * wkg + j) * N + n0 + wn, f32);
        }

        bf16x8 ah = *(const bf16x8*)&Ahi[fa][8 * lg];
        bf16x8 al = *(const bf16x8*)&Alo[fa][8 * lg];
        bf16x8 bh0 = *(const bf16x8*)&Whi[c0][kb0];
        bf16x8 bl0 = *(const bf16x8*)&Wlo[c0][kb0];
        bf16x8 bh1 = *(const bf16x8*)&Whi[c1][kb1];
        bf16x8 bl1 = *(const bf16x8*)&Wlo[c1][kb1];
        acc0 = __builtin_amdgcn_mfma_f32_16x16x32_bf16(ah, bh0, acc0, 0, 0, 0);
        acc0 = __builtin_amdgcn_mfma_f32_16x16x32_bf16(al, bh0, acc0, 0, 0, 0);
        acc0 = __builtin_amdgcn_mfma_f32_16x16x32_bf16(ah, bl0, acc0, 0, 0, 0);
        acc1 = __builtin_amdgcn_mfma_f32_16x16x32_bf16(ah, bh1, acc1, 0, 0, 0);
        acc1 = __builtin_amdgcn_mfma_f32_16x16x32_bf16(al, bh1, acc1, 0, 0, 0);
        acc1 = __builtin_amdgcn_mfma_f32_16x16x32_bf16(ah, bl1, acc1, 0, 0, 0);
    }

    // epilogue: C/D layout col=l15, row=4*lg+r
    const int cm = m0 + 16 * wr + 4 * lg;
    const int cn = n0 + 32 * wc + l15;
    const float b0v = ldx(bias, bOff + cn, f32);
    const float b1v = ldx(bias, bOff + cn + 16, f32);
    if (mode == 0) {
#pragma unroll
        for (int r = 0; r < 4; ++r) {
            float v0 = acc0[r] + b0v;
            float v1 = acc1[r] + b1v;
            if (relu) { v0 = fmaxf(v0, 0.f); v1 = fmaxf(v1, 0.f); }
            C[(size_t)(cm + r) * N + cn]      = v0;
            C[(size_t)(cm + r) * N + cn + 16] = v1;
        }
    } else {
        bf16_t* Cb = (bf16_t*)C;
        const float qs = (z == 0) ? 0.17677669529663687f : 1.0f;   // 1/sqrt(32)
#pragma unroll
        for (int r = 0; r < 4; ++r) {
            float v0 = (acc0[r] + b0v) * qs;
            float v1 = (acc1[r] + b1v) * qs;
            if (z < 2) {
                size_t i0 = (size_t)(cm + r) * 256 + cn;
                bf16_t h0 = (bf16_t)v0;
                Cb[i0]       = h0;
                Cb[M1E + i0] = (bf16_t)(v0 - (float)h0);
                bf16_t h1 = (bf16_t)v1;
                Cb[i0 + 16]       = h1;
                Cb[M1E + i0 + 16] = (bf16_t)(v1 - (float)h1);
            } else {
                Cb[(size_t)cn * 4096 + (cm + r)]        = (bf16_t)v0;
                Cb[(size_t)(cn + 16) * 4096 + (cm + r)] = (bf16_t)v1;
            }
        }
    }
}

// ---------------------------------------------------------------------------
// Swapped-operand MFMA flash attention: zero LDS, zero barriers.
// grid (LD/64, H, B), 256 thr = 4 waves; wave w owns q rows qt*64+w*16..+15.
//
// S^T = mfma(A=K, B=Q): per lane (lg=l>>4, l15=l&15) D gives q=l15 (one q-row
// per lane -> scalar softmax state), keys 16*nt+4*lg+r.
// PV uses the slot permutation sigma(8lg+j) = 16*(2c+(j>>2)) + 4lg + (j&3):
// P fragments are the softmax registers directly (cvt to bf16), V^T loaded
// with sigma applied to its key index (b64 loads from the pre-transposed Vt).
// O emerges as O^T (q=l15, dv=4lg+r) -> two coalesced float4 stores.
__global__ __launch_bounds__(256) void fattn3_kernel(
    const bf16_t* __restrict__ Qb, const bf16_t* __restrict__ Kb,
    const bf16_t* __restrict__ Vt, float* __restrict__ O,
    const int* __restrict__ mask, int causal)
{
    const int tid = threadIdx.x;
    const int qt = blockIdx.x, h = blockIdx.y, b = blockIdx.z;
    const int w = tid >> 6, l = tid & 63, l15 = l & 15, lg = l >> 4;

    // Q fragment (B operand; scale pre-folded by gemm3 mode-1)
    const size_t qoff = ((size_t)(b * LD_ + qt * 64 + w * 16 + l15)) * D_ + h * DK_ + 8 * lg;
    const bf16x8 qh = *(const bf16x8*)(Qb + qoff);
    const bf16x8 ql = *(const bf16x8*)(Qb + M1E + qoff);
    const int q_global = qt * 64 + w * 16 + l15;

    float m = -3.0e38f, lsum = 0.0f;
    f32x4 o0 = {0.f, 0.f, 0.f, 0.f};   // dv = 4lg+r      (q = l15)
    f32x4 o1 = {0.f, 0.f, 0.f, 0.f};   // dv = 16+4lg+r

    const int nkt = causal ? (qt + 1) : (LE_ / 64);

    for (int kt = 0; kt < nkt; ++kt) {
        // ---- K fragments (A operand): same per-lane data as before ----
        const size_t kbase = ((size_t)(b * LE_ + kt * 64)) * D_ + h * DK_ + 8 * lg;
        bf16x8 kh[4], kl[4];
#pragma unroll
        for (int nt = 0; nt < 4; ++nt) {
            size_t off = kbase + (size_t)(nt * 16 + l15) * D_;
            kh[nt] = *(const bf16x8*)(Kb + off);
            kl[nt] = *(const bf16x8*)(Kb + M1E + off);
        }
        // ---- V^T sigma-loads: chunk c, elems j<4 -> key 32c+4lg+j,
        //      elems j>=4 -> key 32c+16+4lg+(j-4) ----
        const bf16_t* vr0 = Vt + (size_t)(h * DK_ + l15) * 4096 + b * 1024 + kt * 64 + 4 * lg;
        const bf16_t* vr1 = vr0 + (size_t)16 * 4096;
        bf16x4 v00a = *(const bf16x4*)(vr0);
        bf16x4 v00b = *(const bf16x4*)(vr0 + 16);
        bf16x4 v01a = *(const bf16x4*)(vr0 + 32);
        bf16x4 v01b = *(const bf16x4*)(vr0 + 48);
        bf16x4 v10a = *(const bf16x4*)(vr1);
        bf16x4 v10b = *(const bf16x4*)(vr1 + 16);
        bf16x4 v11a = *(const bf16x4*)(vr1 + 32);
        bf16x4 v11b = *(const bf16x4*)(vr1 + 48);
        // ---- mask (keys 16nt+4lg+r) ----
        int4 mk[4];
#pragma unroll
        for (int nt = 0; nt < 4; ++nt)
            mk[nt] = *(const int4*)(mask + b * 1024 + kt * 64 + 16 * nt + 4 * lg);

        // ---- S^T = K·Q^T (split bf16: kh*qh + kl*qh + kh*ql) ----
        f32x4 s[4];
#pragma unroll
        for (int nt = 0; nt < 4; ++nt) {
            f32x4 acc = {0.f, 0.f, 0.f, 0.f};
            acc = __builtin_amdgcn_mfma_f32_16x16x32_bf16(kh[nt], qh, acc, 0, 0, 0);
            acc = __builtin_amdgcn_mfma_f32_16x16x32_bf16(kl[nt], qh, acc, 0, 0, 0);
            acc = __builtin_amdgcn_mfma_f32_16x16x32_bf16(kh[nt], ql, acc, 0, 0, 0);
            s[nt] = acc;
        }

        // ---- mask + online softmax (per-lane scalar state; q = l15) ----
        float pm = -3.0e38f;
#pragma unroll
        for (int nt = 0; nt < 4; ++nt) {
#pragma unroll
            for (int r = 0; r < 4; ++r) {
                int key = kt * 64 + 16 * nt + 4 * lg + r;
                int mv = (r == 0) ? mk[nt].x : (r == 1) ? mk[nt].y : (r == 2) ? mk[nt].z : mk[nt].w;
                bool dead = (mv != 0) || (causal && key > q_global);
                float v = dead ? -1e30f : s[nt][r];
                s[nt][r] = v;
                pm = fmaxf(pm, v);
            }
        }
        pm = fmaxf(pm, __shfl_xor(pm, 16));
        pm = fmaxf(pm, __shfl_xor(pm, 32));
        float mnew = fmaxf(m, pm);
        float alpha = __expf(m - mnew);
        m = mnew;
        float psum = 0.f;
#pragma unroll
        for (int nt = 0; nt < 4; ++nt)
#pragma unroll
            for (int r = 0; r < 4; ++r) {
                float p = __expf(s[nt][r] - m);
                s[nt][r] = p;
                psum += p;
            }
        psum += __shfl_xor(psum, 16);
        psum += __shfl_xor(psum, 32);
        lsum = lsum * alpha + psum;
#pragma unroll
        for (int r = 0; r < 4; ++r) { o0[r] *= alpha; o1[r] *= alpha; }

        // ---- P fragments (B operand, in-register via sigma) ----
        bf16x8 pb0, pb1;
#pragma unroll
        for (int r = 0; r < 4; ++r) {
            pb0[r]     = (bf16_t)s[0][r];
            pb0[4 + r] = (bf16_t)s[1][r];
            pb1[r]     = (bf16_t)s[2][r];
            pb1[4 + r] = (bf16_t)s[3][r];
        }
        bf16x8 va00, va01, va10, va11;
#pragma unroll
        for (int r = 0; r < 4; ++r) {
            va00[r] = v00a[r]; va00[4 + r] = v00b[r];
            va01[r] = v01a[r]; va01[4 + r] = v01b[r];
            va10[r] = v10a[r]; va10[4 + r] = v10b[r];
            va11[r] = v11a[r]; va11[4 + r] = v11b[r];
        }
        o0 = __builtin_amdgcn_mfma_f32_16x16x32_bf16(va00, pb0, o0, 0, 0, 0);
        o0 = __builtin_amdgcn_mfma_f32_16x16x32_bf16(va01, pb1, o0, 0, 0, 0);
        o1 = __builtin_amdgcn_mfma_f32_16x16x32_bf16(va10, pb0, o1, 0, 0, 0);
        o1 = __builtin_amdgcn_mfma_f32_16x16x32_bf16(va11, pb1, o1, 0, 0, 0);
    }

    // ---- epilogue: O^T regs -> two float4 stores per lane ----
    const float inv = 1.0f / lsum;
    float* op = O + ((size_t)(b * LD_ + q_global)) * D_ + h * DK_ + 4 * lg;
    f32x4 r0, r1;
#pragma unroll
    for (int r = 0; r < 4; ++r) { r0[r] = o0[r] * inv; r1[r] = o1[r] * inv; }
    *(f32x4*)op = r0;
    *(f32x4*)(op + 16) = r1;
}

// ---------------------------------------------------------------------------
// x = LayerNorm(t + x) * g + b [+ pe]; one wave per token, shfl reduce.
__global__ __launch_bounds__(256) void ln_res_kernel(
    const float* __restrict__ t, float* __restrict__ x,
    const void* __restrict__ g, const void* __restrict__ bt,
    size_t gbOff, const float* __restrict__ pe, int addpe,
    const int* __restrict__ flag)
{
    int f32 = *flag;
    int tok = blockIdx.x * 4 + (threadIdx.x >> 6);
    int l = threadIdx.x & 63;
    size_t base = (size_t)tok * D_ + 4 * l;
    f32x4 tv = *(const f32x4*)(t + base);
    f32x4 xv = *(const f32x4*)(x + base);
    f32x4 v;
    float s1 = 0.f, s2 = 0.f;
#pragma unroll
    for (int j = 0; j < 4; ++j) {
        v[j] = tv[j] + xv[j];
        s1 += v[j];
        s2 += v[j] * v[j];
    }
#pragma unroll
    for (int off = 1; off < 64; off <<= 1) {
        s1 += __shfl_xor(s1, off);
        s2 += __shfl_xor(s2, off);
    }
    float mean = s1 * (1.0f / 256.0f);
    float var  = s2 * (1.0f / 256.0f) - mean * mean;
    float inv  = 1.0f / sqrtf(var + 1e-5f);
    f32x4 out;
#pragma unroll
    for (int j = 0; j < 4; ++j)
        out[j] = (v[j] - mean) * inv * ldx(g, gbOff + 4 * l + j, f32)
               + ldx(bt, gbOff + 4 * l + j, f32);
    if (addpe) {
        size_t pbase = (size_t)(tok & (LD_ - 1)) * D_ + 4 * l;
        f32x4 pv = *(const f32x4*)(pe + pbase);
#pragma unroll
        for (int j = 0; j < 4; ++j) out[j] += pv[j];
    }
    *(f32x4*)(x + base) = out;
}

__global__ __launch_bounds__(256) void cast_kernel(
    const float* __restrict__ x, void* __restrict__ out, const int* __restrict__ flag)
{
    int f32 = *flag;
    int i = blockIdx.x * 256 + threadIdx.x;
    if (f32) ((float*)out)[i] = x[i];
    else ((bf16*)out)[i] = __float2bfloat16(x[i]);
}

// ---------------------------------------------------------------------------
extern "C" void kernel_launch(void* const* d_in, const int* in_sizes, int n_in,
                              void* d_out, int out_size, void* d_ws, size_t ws_size,
                              hipStream_t stream)
{
    const void* enc       = d_in[0];
    const void* dec       = d_in[1];
    const int*  enc_masks = (const int*)d_in[2];
    const int*  dec_masks = (const int*)d_in[3];
    const void* W_tgt = d_in[4];
    const void* b_tgt = d_in[5];
    const void* sa_Wq = d_in[6];
    const void* sa_bq = d_in[7];
    const void* sa_Wk = d_in[8];
    const void* sa_bk = d_in[9];
    const void* sa_Wv = d_in[10];
    const void* sa_bv = d_in[11];
    const void* sa_Wo = d_in[12];
    const void* sa_bo = d_in[13];
    const void* sa_ln_g = d_in[14];
    const void* sa_ln_b = d_in[15];
    const void* ca_Wq = d_in[16];
    const void* ca_bq = d_in[17];
    const void* ca_Wk = d_in[18];
    const void* ca_bk = d_in[19];
    const void* ca_Wv = d_in[20];
    const void* ca_bv = d_in[21];
    const void* ca_Wo = d_in[22];
    const void* ca_bo = d_in[23];
    const void* ca_ln_g = d_in[24];
    const void* ca_ln_b = d_in[25];
    const void* ff_W1 = d_in[26];
    const void* ff_b1 = d_in[27];
    const void* ff_W2 = d_in[28];
    const void* ff_b2 = d_in[29];
    const void* ff_ln_g = d_in[30];
    const void* ff_ln_b = d_in[31];

    const size_t M1 = (size_t)NTOK * D_;        // 1M floats
    float* ws = (float*)d_ws;
    float* x     = ws;                          // [0,1) M1
    float* t     = ws + 1 * M1;                 // [1,2)
    float* ctx   = ws + 2 * M1;                 // [2,3)
    float* enc_f = ws + 3 * M1;                 // [3,4)
    float* h     = ws + 4 * M1;                 // [4,8): NTOK x DFF fp32
    // attention operand buffers alias h (attn phase and FFN phase are disjoint)
    bf16_t* qbuf = (bf16_t*)(ws + 4 * M1);      // hi[M1E] + lo[M1E] = 1 M1 floats
    bf16_t* kbuf = (bf16_t*)(ws + 5 * M1);      // hi[M1E] + lo[M1E]
    bf16_t* vtbuf= (bf16_t*)(ws + 6 * M1);      // [256][4096] bf16 = 0.5 M1
    float* pe    = ws + 8 * M1;                 // [8, 8.25): LD_*D_ floats
    int*   flag  = (int*)(ws + 9 * M1);

    const int nElem = NTOK * D_;                // 1,048,576

    detect_kernel<<<1, 256, 0, stream>>>(enc, flag);
    pe_build_kernel<<<(LD_ * D_) / 256, 256, 0, stream>>>(pe);
    embed_kernel<<<nElem / 256, 256, 0, stream>>>(dec, W_tgt, b_tgt, x, pe, flag);
    conv_kernel<<<nElem / 256, 256, 0, stream>>>(enc, enc_f, flag);

    dim3 gProj(D_ / 64, NTOK / 32, 3);          // (4,128,3)
    dim3 gOne(D_ / 64, NTOK / 32, 1);           // (4,128,1)
    dim3 gFF1(DFF_ / 64, NTOK / 32, 1);         // (16,128,1)
    dim3 gAttn(LD_ / 64, H_, B_);               // (16,8,4)

    for (int i = 0; i < NL_; ++i) {
        const size_t wOff  = (size_t)i * D_ * D_;      // element offsets
        const size_t bOff  = (size_t)i * D_;
        const size_t f1Off = (size_t)i * D_ * DFF_;
        const size_t f1bOff= (size_t)i * DFF_;

        // --- self attention ---
        gemm3_kernel<<<gProj, 256, 0, stream>>>(
            x, x, x, sa_Wq, sa_Wk, sa_Wv, sa_bq, sa_bk, sa_bv,
            (float*)qbuf, (float*)kbuf, (float*)vtbuf,
            wOff, bOff, NTOK, D_, D_, 0, 1, flag);
        fattn3_kernel<<<gAttn, 256, 0, stream>>>(qbuf, kbuf, vtbuf, ctx, dec_masks, 1);
        gemm3_kernel<<<gOne, 256, 0, stream>>>(
            ctx, ctx, ctx, sa_Wo, sa_Wo, sa_Wo, sa_bo, sa_bo, sa_bo,
            t, t, t, wOff, bOff, NTOK, D_, D_, 0, 0, flag);
        ln_res_kernel<<<NTOK / 4, 256, 0, stream>>>(t, x, sa_ln_g, sa_ln_b, bOff, pe, 0, flag);

        // --- cross attention ---
        gemm3_kernel<<<gProj, 256, 0, stream>>>(
            x, enc_f, enc_f, ca_Wq, ca_Wk, ca_Wv, ca_bq, ca_bk, ca_bv,
            (float*)qbuf, (float*)kbuf, (float*)vtbuf,
            wOff, bOff, NTOK, D_, D_, 0, 1, flag);
        fattn3_kernel<<<gAttn, 256, 0, stream>>>(qbuf, kbuf, vtbuf, ctx, enc_masks, 0);
        gemm3_kernel<<<gOne, 256, 0, stream>>>(
            ctx, ctx, ctx, ca_Wo, ca_Wo, ca_Wo, ca_bo, ca_bo, ca_bo,
            t, t, t, wOff, bOff, NTOK, D_, D_, 0, 0, flag);
        ln_res_kernel<<<NTOK / 4, 256, 0, stream>>>(t, x, ca_ln_g, ca_ln_b, bOff, pe, 0, flag);

        // --- FFN (PE for next layer fused into ff-LN, except last layer) ---
        gemm3_kernel<<<gFF1, 256, 0, stream>>>(
            x, x, x, ff_W1, ff_W1, ff_W1, ff_b1, ff_b1, ff_b1,
            h, h, h, f1Off, f1bOff, NTOK, DFF_, D_, 1, 0, flag);
        gemm3_kernel<<<gOne, 256, 0, stream>>>(
            h, h, h, ff_W2, ff_W2, ff_W2, ff_b2, ff_b2, ff_b2,
            t, t, t, f1Off, bOff, NTOK, D_, DFF_, 0, 0, flag);
        ln_res_kernel<<<NTOK / 4, 256, 0, stream>>>(
            t, x, ff_ln_g, ff_ln_b, bOff, pe, (i < NL_ - 1) ? 1 : 0, flag);
    }

    cast_kernel<<<nElem / 256, 256, 0, stream>>>(x, d_out, flag);
}

// Round 5
// 1100.251 us; speedup vs baseline: 1.4622x; 1.4622x over previous
//
#include <hip/hip_runtime.h>
#include <hip/hip_bf16.h>

#define B_   4
#define LD_  1024
#define LE_  1024
#define D_   256
#define H_   8
#define DK_  32
#define DFF_ 1024
#define NL_  6
#define NTOK (B_ * LD_)   // 4096 decoder tokens; encoder also 4*1024 = 4096
#define M1E  1048576      // NTOK * D_ elements

typedef __hip_bfloat16 bf16;
typedef __bf16 bf16_t;
typedef bf16_t bf16x8 __attribute__((ext_vector_type(8)));
typedef bf16_t bf16x4 __attribute__((ext_vector_type(4)));
typedef float  f32x4  __attribute__((ext_vector_type(4)));

__device__ __forceinline__ float bits2f(unsigned short u) {
    union { unsigned int i; float f; } w; w.i = ((unsigned int)u) << 16; return w.f;
}
// dtype-flexible scalar load from tensor base + element index
__device__ __forceinline__ float ldx(const void* p, size_t i, int f32) {
    if (f32) return ((const float*)p)[i];
    return bits2f(((const unsigned short*)p)[i]);
}

// ---------------------------------------------------------------------------
// Detect input dtype (bf16 vs fp32). flag: 1=fp32, 0=bf16.
__global__ __launch_bounds__(256) void detect_kernel(
    const void* __restrict__ enc, int* __restrict__ flag)
{
    __shared__ int bad;
    if (threadIdx.x == 0) bad = 0;
    __syncthreads();
    const unsigned short* u = (const unsigned short*)enc;
    int b = 0;
    for (int i = threadIdx.x; i < 4096; i += 256) {
        unsigned short e = (u[i] >> 7) & 0xFF;
        if (e >= 142) b = 1;
    }
    if (b) atomicOr(&bad, 1);
    __syncthreads();
    if (threadIdx.x == 0) *flag = bad;
}

// ---------------------------------------------------------------------------
// build PE table [1024][256] once
__global__ __launch_bounds__(256) void pe_build_kernel(float* __restrict__ pe)
{
    int i = blockIdx.x * 256 + threadIdx.x;     // over LD_*D_ = 262144
    int d = i & (D_ - 1);
    int pos = i >> 8;
    int j = d & 127;
    float inv = powf(10000.0f, -2.0f * (float)j / (float)D_);
    float s = (float)pos * inv;
    pe[i] = (d < 128) ? sinf(s) : cosf(s);
}

// x = embed + PE (layer-0 PE fused here)
__global__ __launch_bounds__(256) void embed_kernel(
    const void* __restrict__ dec, const void* __restrict__ Wt,
    const void* __restrict__ bt, float* __restrict__ x,
    const float* __restrict__ pe, const int* __restrict__ flag)
{
    int f32 = *flag;
    int i = blockIdx.x * 256 + threadIdx.x;     // over NTOK * D_
    int d = i & (D_ - 1);
    int t = i >> 8;
    float a0 = ldx(dec, t * 3 + 0, f32);
    float a1 = ldx(dec, t * 3 + 1, f32);
    float a2 = ldx(dec, t * 3 + 2, f32);
    x[i] = ldx(bt, d, f32) + a0 * ldx(Wt, 0 * D_ + d, f32)
         + a1 * ldx(Wt, 1 * D_ + d, f32) + a2 * ldx(Wt, 2 * D_ + d, f32)
         + pe[i & (LD_ * D_ - 1)];
}

__global__ __launch_bounds__(256) void conv_kernel(
    const void* __restrict__ in, float* __restrict__ out, const int* __restrict__ flag)
{
    int f32 = *flag;
    int i = blockIdx.x * 256 + threadIdx.x;
    out[i] = ldx(in, i, f32);
}

// ---------------------------------------------------------------------------
// MFMA GEMM: C = A @ W + bias (optional relu). A fp32 [M,K]; W,bias dtype per
// flag; wOff/bOff = element offsets of the layer slice. z-batched over up to 3
// independent (A,W,bias,C) tuples.
//
// bf16 fast path (flag==0): weights are exactly bf16 -> Wlo == 0 identically,
// so the Ah*Wl term and all Wlo staging are skipped (bit-identical result).
//
// mode 0: C fp32 [M][N] (+optional relu)
// mode 1: attention-prep epilogue (N==256), FRAGMENT-READY layouts:
//   z==0 (Q) / z==1 (K): per (b,h,16-row-block qw): 64-lane x 8 bf16 fragment,
//     hi at blockbase+lane*8, lo at blockbase+512+lane*8.
//     blockbase = ((b*8+h)*64 + qw)*1024.
//   z==2 (V): sigma-permuted PV A-fragments:
//     base = ((b*8+h)*16 + kt)*2048 + c*1024 + dvh*512 + lane*8 + j,
//     element (lane=lg*16+l15, j) = V[key=kt*64+c*32+16*(j>>2)+4*lg+(j&3)]
//                                     [h*32 + dvh*16 + l15]
__global__ __launch_bounds__(256) void gemm3_kernel(
    const float* __restrict__ A0, const float* __restrict__ A1, const float* __restrict__ A2,
    const void* __restrict__ W0, const void* __restrict__ W1, const void* __restrict__ W2,
    const void* __restrict__ bias0, const void* __restrict__ bias1, const void* __restrict__ bias2,
    float* __restrict__ C0, float* __restrict__ C1, float* __restrict__ C2,
    size_t wOff, size_t bOff,
    int M, int N, int K, int relu, int mode, const int* __restrict__ flag)
{
    const int f32 = *flag;
    const int z = blockIdx.z;
    const float* A = (z == 0) ? A0 : (z == 1) ? A1 : A2;
    const void*  W = (z == 0) ? W0 : (z == 1) ? W1 : W2;
    const void*  bias = (z == 0) ? bias0 : (z == 1) ? bias1 : bias2;
    float* C = (z == 0) ? C0 : (z == 1) ? C1 : C2;

    __shared__ __align__(16) bf16_t Ahi[32][40];
    __shared__ __align__(16) bf16_t Alo[32][40];
    __shared__ __align__(16) bf16_t Whi[64][40];
    __shared__ __align__(16) bf16_t Wlo[64][40];

    const int tid = threadIdx.x;
    const int m0 = blockIdx.y * 32, n0 = blockIdx.x * 64;
    const int w = tid >> 6, l = tid & 63, l15 = l & 15, lg = l >> 4;
    const int wr = w >> 1, wc = w & 1;

    // A staging: thread -> (row 0..31, 4-float group)
    const int ar = tid >> 3, ac = (tid & 7) * 4;
    // W staging: thread -> (col n 0..63, k-block 0..3); swizzled block index
    const int wn = tid & 63, wkg = tid >> 6;
    const int wkb = 8 * (wkg ^ ((wn >> 3) & 3));

    // fragment read indices (hoisted)
    const int fa = 16 * wr + l15;
    const int c0 = 32 * wc + l15, c1 = c0 + 16;
    const int kb0 = 8 * (lg ^ ((c0 >> 3) & 3));
    const int kb1 = 8 * (lg ^ ((c1 >> 3) & 3));

    f32x4 acc0 = {0.f, 0.f, 0.f, 0.f};
    f32x4 acc1 = {0.f, 0.f, 0.f, 0.f};

    // prefetch K-step 0
    float4 av = *(const float4*)&A[(size_t)(m0 + ar) * K + ac];
    float wf[8];
#pragma unroll
    for (int j = 0; j < 8; ++j)
        wf[j] = ldx(W, wOff + (size_t)(8 * wkg + j) * N + n0 + wn, f32);

    for (int k0 = 0; k0 < K; k0 += 32) {
        __syncthreads();
        {   // convert staged regs -> hi/lo LDS
            float af[4] = {av.x, av.y, av.z, av.w};
            bf16x4 h4, l4;
#pragma unroll
            for (int j = 0; j < 4; ++j) {
                bf16_t hv = (bf16_t)af[j];
                h4[j] = hv;
                l4[j] = (bf16_t)(af[j] - (float)hv);
            }
            *(bf16x4*)&Ahi[ar][ac] = h4;
            *(bf16x4*)&Alo[ar][ac] = l4;
            bf16x8 h8;
#pragma unroll
            for (int j = 0; j < 8; ++j) h8[j] = (bf16_t)wf[j];
            *(bf16x8*)&Whi[wn][wkb] = h8;
            if (f32) {
                bf16x8 l8;
#pragma unroll
                for (int j = 0; j < 8; ++j) l8[j] = (bf16_t)(wf[j] - (float)((bf16_t)wf[j]));
                *(bf16x8*)&Wlo[wn][wkb] = l8;
            }
        }
        __syncthreads();

        // prefetch next K-step while MFMAs run
        if (k0 + 32 < K) {
            av = *(const float4*)&A[(size_t)(m0 + ar) * K + k0 + 32 + ac];
#pragma unroll
            for (int j = 0; j < 8; ++j)
                wf[j] = ldx(W, wOff + (size_t)(k0 + 32 + 8 * wkg + j) * N + n0 + wn, f32);
        }

        bf16x8 ah = *(const bf16x8*)&Ahi[fa][8 * lg];
        bf16x8 al = *(const bf16x8*)&Alo[fa][8 * lg];
        bf16x8 bh0 = *(const bf16x8*)&Whi[c0][kb0];
        bf16x8 bh1 = *(const bf16x8*)&Whi[c1][kb1];
        acc0 = __builtin_amdgcn_mfma_f32_16x16x32_bf16(ah, bh0, acc0, 0, 0, 0);
        acc0 = __builtin_amdgcn_mfma_f32_16x16x32_bf16(al, bh0, acc0, 0, 0, 0);
        acc1 = __builtin_amdgcn_mfma_f32_16x16x32_bf16(ah, bh1, acc1, 0, 0, 0);
        acc1 = __builtin_amdgcn_mfma_f32_16x16x32_bf16(al, bh1, acc1, 0, 0, 0);
        if (f32) {
            bf16x8 bl0 = *(const bf16x8*)&Wlo[c0][kb0];
            bf16x8 bl1 = *(const bf16x8*)&Wlo[c1][kb1];
            acc0 = __builtin_amdgcn_mfma_f32_16x16x32_bf16(ah, bl0, acc0, 0, 0, 0);
            acc1 = __builtin_amdgcn_mfma_f32_16x16x32_bf16(ah, bl1, acc1, 0, 0, 0);
        }
    }

    // epilogue: C/D layout col=l15, row=4*lg+r
    const int cm = m0 + 16 * wr + 4 * lg;
    const int cn = n0 + 32 * wc + l15;
    const float b0v = ldx(bias, bOff + cn, f32);
    const float b1v = ldx(bias, bOff + cn + 16, f32);
    if (mode == 0) {
#pragma unroll
        for (int r = 0; r < 4; ++r) {
            float v0 = acc0[r] + b0v;
            float v1 = acc1[r] + b1v;
            if (relu) { v0 = fmaxf(v0, 0.f); v1 = fmaxf(v1, 0.f); }
            C[(size_t)(cm + r) * N + cn]      = v0;
            C[(size_t)(cm + r) * N + cn + 16] = v1;
        }
    } else {
        bf16_t* Cb = (bf16_t*)C;
        const float qs = (z == 0) ? 0.17677669529663687f : 1.0f;   // 1/sqrt(32)
#pragma unroll
        for (int r = 0; r < 4; ++r) {
            const int token = cm + r;
#pragma unroll
            for (int cc = 0; cc < 2; ++cc) {
                const int d = cn + 16 * cc;
                const float v = ((cc == 0 ? acc0[r] : acc1[r]) + (cc == 0 ? b0v : b1v)) * qs;
                if (z < 2) {
                    int bb = token >> 10, qw = (token >> 4) & 63, lt = token & 15;
                    int hh = d >> 5, lg2 = (d >> 3) & 3, jj = d & 7;
                    size_t base = ((size_t)((bb * 8 + hh) * 64 + qw)) * 1024
                                + (size_t)(lg2 * 16 + lt) * 8 + jj;
                    bf16_t hv = (bf16_t)v;
                    Cb[base]       = hv;
                    Cb[base + 512] = (bf16_t)(v - (float)hv);
                } else {
                    int bb = token >> 10, ktt = (token >> 6) & 15, c2 = (token >> 5) & 1;
                    int w32 = token & 31;
                    int lg2 = (w32 >> 2) & 3, jj = (w32 >> 4) * 4 + (w32 & 3);
                    int hh = d >> 5, dvh = (d >> 4) & 1, lt = d & 15;
                    size_t base = ((size_t)((bb * 8 + hh) * 16 + ktt)) * 2048
                                + c2 * 1024 + dvh * 512 + (size_t)(lg2 * 16 + lt) * 8 + jj;
                    Cb[base] = (bf16_t)v;
                }
            }
        }
    }
}

// ---------------------------------------------------------------------------
// Swapped-operand MFMA flash attention, fragment-ready operands, register
// double-buffered. Zero LDS, zero barriers. grid (LD/64, H, B), 256 thr =
// 4 independent waves; wave w owns q rows qt*64+w*16..+15 (one q-row/lane).
// All loads are coalesced 1KB b128s (lane*16B within a fragment block).
__global__ __launch_bounds__(256) void fattn4_kernel(
    const bf16_t* __restrict__ Qf, const bf16_t* __restrict__ Kf,
    const bf16_t* __restrict__ Vf, float* __restrict__ O,
    const int* __restrict__ mask, int causal)
{
    const int tid = threadIdx.x;
    const int qt = blockIdx.x, h = blockIdx.y, b = blockIdx.z;
    const int w = tid >> 6, l = tid & 63, l15 = l & 15, lg = l >> 4;
    const int bh = b * H_ + h;

    // Q fragments (scale pre-folded)
    const size_t qbase = ((size_t)(bh * 64 + qt * 4 + w)) * 1024 + l * 8;
    const bf16x8 qh = *(const bf16x8*)(Qf + qbase);
    const bf16x8 ql = *(const bf16x8*)(Qf + qbase + 512);
    const int q_global = qt * 64 + w * 16 + l15;

    const bf16_t* kp = Kf + (size_t)bh * 64 * 1024 + l * 8;   // + kb*1024 (+512 lo)
    const bf16_t* vp = Vf + (size_t)bh * 16 * 2048 + l * 8;   // + kt*2048 + c*1024 + dvh*512
    const int*    mp = mask + b * 1024 + 4 * lg;              // + kt*64 + nt*16

    float m = -3.0e38f, lsum = 0.0f;
    f32x4 o0 = {0.f, 0.f, 0.f, 0.f};   // dv = dvh0: h*32 + l15
    f32x4 o1 = {0.f, 0.f, 0.f, 0.f};   // dv = dvh1: h*32 + 16 + l15

    const int nkt = causal ? (qt + 1) : (LE_ / 64);

    bf16x8 kha[4], kla[4], vaa[4];  int4 mka[4];
    bf16x8 khb[4], klb[4], vab[4];  int4 mkb[4];

#define FA_LOAD(kh_, kl_, va_, mk_, KT) do {                                    \
    _Pragma("unroll")                                                           \
    for (int nt = 0; nt < 4; ++nt) {                                            \
        kh_[nt] = *(const bf16x8*)(kp + (size_t)(KT) * 4096 + nt * 1024);       \
        kl_[nt] = *(const bf16x8*)(kp + (size_t)(KT) * 4096 + nt * 1024 + 512); \
    }                                                                           \
    va_[0] = *(const bf16x8*)(vp + (size_t)(KT) * 2048);                        \
    va_[1] = *(const bf16x8*)(vp + (size_t)(KT) * 2048 + 1024);                 \
    va_[2] = *(const bf16x8*)(vp + (size_t)(KT) * 2048 + 512);                  \
    va_[3] = *(const bf16x8*)(vp + (size_t)(KT) * 2048 + 1536);                 \
    _Pragma("unroll")                                                           \
    for (int nt = 0; nt < 4; ++nt)                                              \
        mk_[nt] = *(const int4*)(mp + (KT) * 64 + nt * 16);                     \
} while (0)

#define FA_COMPUTE(kh_, kl_, va_, mk_, KT) do {                                 \
    f32x4 s[4];                                                                 \
    _Pragma("unroll")                                                           \
    for (int nt = 0; nt < 4; ++nt) {                                            \
        f32x4 acc = {0.f, 0.f, 0.f, 0.f};                                       \
        acc = __builtin_amdgcn_mfma_f32_16x16x32_bf16(kh_[nt], qh, acc, 0,0,0); \
        acc = __builtin_amdgcn_mfma_f32_16x16x32_bf16(kl_[nt], qh, acc, 0,0,0); \
        acc = __builtin_amdgcn_mfma_f32_16x16x32_bf16(kh_[nt], ql, acc, 0,0,0); \
        s[nt] = acc;                                                            \
    }                                                                           \
    float pm = -3.0e38f;                                                        \
    _Pragma("unroll")                                                           \
    for (int nt = 0; nt < 4; ++nt) {                                            \
        _Pragma("unroll")                                                       \
        for (int r = 0; r < 4; ++r) {                                           \
            int key = (KT) * 64 + 16 * nt + 4 * lg + r;                         \
            int mv = (r==0)?mk_[nt].x:(r==1)?mk_[nt].y:(r==2)?mk_[nt].z:mk_[nt].w; \
            bool dead = (mv != 0) || (causal && key > q_global);                \
            float v = dead ? -1e30f : s[nt][r];                                 \
            s[nt][r] = v;                                                       \
            pm = fmaxf(pm, v);                                                  \
        }                                                                       \
    }                                                                           \
    pm = fmaxf(pm, __shfl_xor(pm, 16));                                         \
    pm = fmaxf(pm, __shfl_xor(pm, 32));                                         \
    float mnew = fmaxf(m, pm);                                                  \
    float alpha = __expf(m - mnew);                                             \
    m = mnew;                                                                   \
    float psum = 0.f;                                                           \
    _Pragma("unroll")                                                           \
    for (int nt = 0; nt < 4; ++nt) {                                            \
        _Pragma("unroll")                                                       \
        for (int r = 0; r < 4; ++r) {                                           \
            float p = __expf(s[nt][r] - m);                                     \
            s[nt][r] = p;                                                       \
            psum += p;                                                          \
        }                                                                       \
    }                                                                           \
    psum += __shfl_xor(psum, 16);                                               \
    psum += __shfl_xor(psum, 32);                                               \
    lsum = lsum * alpha + psum;                                                 \
    _Pragma("unroll")                                                           \
    for (int r = 0; r < 4; ++r) { o0[r] *= alpha; o1[r] *= alpha; }             \
    bf16x8 pb0, pb1;                                                            \
    _Pragma("unroll")                                                           \
    for (int r = 0; r < 4; ++r) {                                               \
        pb0[r]     = (bf16_t)s[0][r];  pb0[4 + r] = (bf16_t)s[1][r];            \
        pb1[r]     = (bf16_t)s[2][r];  pb1[4 + r] = (bf16_t)s[3][r];            \
    }                                                                           \
    o0 = __builtin_amdgcn_mfma_f32_16x16x32_bf16(va_[0], pb0, o0, 0, 0, 0);     \
    o0 = __builtin_amdgcn_mfma_f32_16x16x32_bf16(va_[1], pb1, o0, 0, 0, 0);     \
    o1 = __builtin_amdgcn_mfma_f32_16x16x32_bf16(va_[2], pb0, o1, 0, 0, 0);     \
    o1 = __builtin_amdgcn_mfma_f32_16x16x32_bf16(va_[3], pb1, o1, 0, 0, 0);     \
} while (0)

    FA_LOAD(kha, kla, vaa, mka, 0);
    int kt = 0;
    for (; kt + 2 <= nkt; kt += 2) {
        FA_LOAD(khb, klb, vab, mkb, kt + 1);
        FA_COMPUTE(kha, kla, vaa, mka, kt);
        if (kt + 2 < nkt) FA_LOAD(kha, kla, vaa, mka, kt + 2);
        FA_COMPUTE(khb, klb, vab, mkb, kt + 1);
    }
    if (kt < nkt) FA_COMPUTE(kha, kla, vaa, mka, kt);

#undef FA_LOAD
#undef FA_COMPUTE

    // ---- epilogue: O^T regs (q=l15, dv per reg) -> two float4 stores ----
    const float inv = 1.0f / lsum;
    float* op = O + ((size_t)(b * LD_ + q_global)) * D_ + h * DK_ + 4 * lg;
    f32x4 r0, r1;
#pragma unroll
    for (int r = 0; r < 4; ++r) { r0[r] = o0[r] * inv; r1[r] = o1[r] * inv; }
    *(f32x4*)op = r0;
    *(f32x4*)(op + 16) = r1;
}

// ---------------------------------------------------------------------------
// x = LayerNorm(t + x) * g + b [+ pe]; one wave per token, shfl reduce.
__global__ __launch_bounds__(256) void ln_res_kernel(
    const float* __restrict__ t, float* __restrict__ x,
    const void* __restrict__ g, const void* __restrict__ bt,
    size_t gbOff, const float* __restrict__ pe, int addpe,
    const int* __restrict__ flag)
{
    int f32 = *flag;
    int tok = blockIdx.x * 4 + (threadIdx.x >> 6);
    int l = threadIdx.x & 63;
    size_t base = (size_t)tok * D_ + 4 * l;
    f32x4 tv = *(const f32x4*)(t + base);
    f32x4 xv = *(const f32x4*)(x + base);
    f32x4 v;
    float s1 = 0.f, s2 = 0.f;
#pragma unroll
    for (int j = 0; j < 4; ++j) {
        v[j] = tv[j] + xv[j];
        s1 += v[j];
        s2 += v[j] * v[j];
    }
#pragma unroll
    for (int off = 1; off < 64; off <<= 1) {
        s1 += __shfl_xor(s1, off);
        s2 += __shfl_xor(s2, off);
    }
    float mean = s1 * (1.0f / 256.0f);
    float var  = s2 * (1.0f / 256.0f) - mean * mean;
    float inv  = 1.0f / sqrtf(var + 1e-5f);
    f32x4 out;
#pragma unroll
    for (int j = 0; j < 4; ++j)
        out[j] = (v[j] - mean) * inv * ldx(g, gbOff + 4 * l + j, f32)
               + ldx(bt, gbOff + 4 * l + j, f32);
    if (addpe) {
        size_t pbase = (size_t)(tok & (LD_ - 1)) * D_ + 4 * l;
        f32x4 pv = *(const f32x4*)(pe + pbase);
#pragma unroll
        for (int j = 0; j < 4; ++j) out[j] += pv[j];
    }
    *(f32x4*)(x + base) = out;
}

__global__ __launch_bounds__(256) void cast_kernel(
    const float* __restrict__ x, void* __restrict__ out, const int* __restrict__ flag)
{
    int f32 = *flag;
    int i = blockIdx.x * 256 + threadIdx.x;
    if (f32) ((float*)out)[i] = x[i];
    else ((bf16*)out)[i] = __float2bfloat16(x[i]);
}

// ---------------------------------------------------------------------------
extern "C" void kernel_launch(void* const* d_in, const int* in_sizes, int n_in,
                              void* d_out, int out_size, void* d_ws, size_t ws_size,
                              hipStream_t stream)
{
    const void* enc       = d_in[0];
    const void* dec       = d_in[1];
    const int*  enc_masks = (const int*)d_in[2];
    const int*  dec_masks = (const int*)d_in[3];
    const void* W_tgt = d_in[4];
    const void* b_tgt = d_in[5];
    const void* sa_Wq = d_in[6];
    const void* sa_bq = d_in[7];
    const void* sa_Wk = d_in[8];
    const void* sa_bk = d_in[9];
    const void* sa_Wv = d_in[10];
    const void* sa_bv = d_in[11];
    const void* sa_Wo = d_in[12];
    const void* sa_bo = d_in[13];
    const void* sa_ln_g = d_in[14];
    const void* sa_ln_b = d_in[15];
    const void* ca_Wq = d_in[16];
    const void* ca_bq = d_in[17];
    const void* ca_Wk = d_in[18];
    const void* ca_bk = d_in[19];
    const void* ca_Wv = d_in[20];
    const void* ca_bv = d_in[21];
    const void* ca_Wo = d_in[22];
    const void* ca_bo = d_in[23];
    const void* ca_ln_g = d_in[24];
    const void* ca_ln_b = d_in[25];
    const void* ff_W1 = d_in[26];
    const void* ff_b1 = d_in[27];
    const void* ff_W2 = d_in[28];
    const void* ff_b2 = d_in[29];
    const void* ff_ln_g = d_in[30];
    const void* ff_ln_b = d_in[31];

    const size_t M1 = (size_t)NTOK * D_;        // 1M floats
    float* ws = (float*)d_ws;
    float* x     = ws;                          // [0,1) M1
    float* t     = ws + 1 * M1;                 // [1,2)
    float* ctx   = ws + 2 * M1;                 // [2,3)
    float* enc_f = ws + 3 * M1;                 // [3,4)
    float* h     = ws + 4 * M1;                 // [4,8): NTOK x DFF fp32
    // attention operand buffers alias h (attn phase and FFN phase are disjoint)
    bf16_t* qbuf = (bf16_t*)(ws + 4 * M1);      // frag-ready hi/lo, 2*M1E bf16
    bf16_t* kbuf = (bf16_t*)(ws + 5 * M1);      // frag-ready hi/lo, 2*M1E bf16
    bf16_t* vtbuf= (bf16_t*)(ws + 6 * M1);      // sigma-frag V, M1E bf16
    float* pe    = ws + 8 * M1;                 // [8, 8.25): LD_*D_ floats
    int*   flag  = (int*)(ws + 9 * M1);

    const int nElem = NTOK * D_;                // 1,048,576

    detect_kernel<<<1, 256, 0, stream>>>(enc, flag);
    pe_build_kernel<<<(LD_ * D_) / 256, 256, 0, stream>>>(pe);
    embed_kernel<<<nElem / 256, 256, 0, stream>>>(dec, W_tgt, b_tgt, x, pe, flag);
    conv_kernel<<<nElem / 256, 256, 0, stream>>>(enc, enc_f, flag);

    dim3 gProj(D_ / 64, NTOK / 32, 3);          // (4,128,3)
    dim3 gOne(D_ / 64, NTOK / 32, 1);           // (4,128,1)
    dim3 gFF1(DFF_ / 64, NTOK / 32, 1);         // (16,128,1)
    dim3 gAttn(LD_ / 64, H_, B_);               // (16,8,4)

    for (int i = 0; i < NL_; ++i) {
        const size_t wOff  = (size_t)i * D_ * D_;      // element offsets
        const size_t bOff  = (size_t)i * D_;
        const size_t f1Off = (size_t)i * D_ * DFF_;
        const size_t f1bOff= (size_t)i * DFF_;

        // --- self attention ---
        gemm3_kernel<<<gProj, 256, 0, stream>>>(
            x, x, x, sa_Wq, sa_Wk, sa_Wv, sa_bq, sa_bk, sa_bv,
            (float*)qbuf, (float*)kbuf, (float*)vtbuf,
            wOff, bOff, NTOK, D_, D_, 0, 1, flag);
        fattn4_kernel<<<gAttn, 256, 0, stream>>>(qbuf, kbuf, vtbuf, ctx, dec_masks, 1);
        gemm3_kernel<<<gOne, 256, 0, stream>>>(
            ctx, ctx, ctx, sa_Wo, sa_Wo, sa_Wo, sa_bo, sa_bo, sa_bo,
            t, t, t, wOff, bOff, NTOK, D_, D_, 0, 0, flag);
        ln_res_kernel<<<NTOK / 4, 256, 0, stream>>>(t, x, sa_ln_g, sa_ln_b, bOff, pe, 0, flag);

        // --- cross attention ---
        gemm3_kernel<<<gProj, 256, 0, stream>>>(
            x, enc_f, enc_f, ca_Wq, ca_Wk, ca_Wv, ca_bq, ca_bk, ca_bv,
            (float*)qbuf, (float*)kbuf, (float*)vtbuf,
            wOff, bOff, NTOK, D_, D_, 0, 1, flag);
        fattn4_kernel<<<gAttn, 256, 0, stream>>>(qbuf, kbuf, vtbuf, ctx, enc_masks, 0);
        gemm3_kernel<<<gOne, 256, 0, stream>>>(
            ctx, ctx, ctx, ca_Wo, ca_Wo, ca_Wo, ca_bo, ca_bo, ca_bo,
            t, t, t, wOff, bOff, NTOK, D_, D_, 0, 0, flag);
        ln_res_kernel<<<NTOK / 4, 256, 0, stream>>>(t, x, ca_ln_g, ca_ln_b, bOff, pe, 0, flag);

        // --- FFN (PE for next layer fused into ff-LN, except last layer) ---
        gemm3_kernel<<<gFF1, 256, 0, stream>>>(
            x, x, x, ff_W1, ff_W1, ff_W1, ff_b1, ff_b1, ff_b1,
            h, h, h, f1Off, f1bOff, NTOK, DFF_, D_, 1, 0, flag);
        gemm3_kernel<<<gOne, 256, 0, stream>>>(
            h, h, h, ff_W2, ff_W2, ff_W2, ff_b2, ff_b2, ff_b2,
            t, t, t, f1Off, bOff, NTOK, D_, DFF_, 0, 0, flag);
        ln_res_kernel<<<NTOK / 4, 256, 0, stream>>>(
            t, x, ff_ln_g, ff_ln_b, bOff, pe, (i < NL_ - 1) ? 1 : 0, flag);
    }

    cast_kernel<<<nElem / 256, 256, 0, stream>>>(x, d_out, flag);
}